// Round 7
// baseline (99.409 us; speedup 1.0000x reference)
//
#include <hip/hip_runtime.h>

// ConvNearestNeighbor forward, MI355X (gfx950).
// x: (B=16, C=32, H=32, W=32) f32; neighbors: (NUM=32, C=32, 9) f32
// out[((b*NUM + n)*C + c)*H*W + h*W + w]
//   = max_k | x[b,c,h-row_k,w-col_k] (zero-pad) - neighbors[n,c,k] |,
//   k = 3*(row+1)+(col+1), row,col in {-1,0,1}
//
// Round 7: CONTIGUOUS-STORE remap (final falsification of the "scattered
// 4KB store chunks cap at ~1.8TB/s" theory). Block = ((b,n), c-group of 8):
// each block writes ONE contiguous 32KB span; the 4 y-siblings of an (b,n)
// pair tile a contiguous 128KB. Previous rounds' blocks wrote 4KB chunks at
// 128KB strides. x windows read direct from global (2MiB, L2-hot);
// neighbors are block-uniform -> s_load broadcasts. Grid 2048, 8 blocks/CU.

#define BB 16
#define CC 32
#define HH 32
#define WW 32
#define NUMN 32
#define CPB 8    // c-planes per block

typedef float f32x4 __attribute__((ext_vector_type(4)));

__global__ __launch_bounds__(256) void conv_nn_kernel(
    const float* __restrict__ x,
    const float* __restrict__ neighbors,
    float* __restrict__ out)
{
    const int bn = blockIdx.x;        // 0 .. B*NUM-1
    const int b  = bn >> 5;           // / NUM
    const int n  = bn & 31;           // % NUM
    const int c0 = blockIdx.y * CPB;  // first c-plane for this block
    const int t  = threadIdx.x;       // 0..255

    // thread -> (h, w0..w0+3); plane-linear offset = h*W + w0 = 4*t
    const int h  = t >> 3;
    const int w0 = (t & 7) * 4;       // 16B-aligned column

    const int row0 = h - 1, row2 = h + 1;
    const bool rv0 = (row0 >= 0);
    const bool rv2 = (row2 < HH);
    const bool lv  = (w0 > 0);
    const bool rgt = (w0 + 4 < WW);

    // output: fully contiguous 32KB span per block
    float* obase = out + ((size_t)(b * NUMN + n) * CC + c0) * (HH * WW) + t * 4;

    #pragma unroll 2
    for (int ci = 0; ci < CPB; ++ci) {
        const int c = c0 + ci;
        const float* __restrict__ rp1 = x + (b * CC + c) * (HH * WW) + h * WW;

        // 3x6 zero-padded window
        float xr[3][6];
        {
            const float* rp0 = rp1 - WW;
            const float* rp2 = rp1 + WW;
            f32x4 m0 = {0,0,0,0}, m1, m2 = {0,0,0,0};
            if (rv0) m0 = *reinterpret_cast<const f32x4*>(rp0 + w0);
            m1 = *reinterpret_cast<const f32x4*>(rp1 + w0);
            if (rv2) m2 = *reinterpret_cast<const f32x4*>(rp2 + w0);
            xr[0][0] = (rv0 && lv)  ? rp0[w0 - 1] : 0.0f;
            xr[0][5] = (rv0 && rgt) ? rp0[w0 + 4] : 0.0f;
            xr[1][0] = lv  ? rp1[w0 - 1] : 0.0f;
            xr[1][5] = rgt ? rp1[w0 + 4] : 0.0f;
            xr[2][0] = (rv2 && lv)  ? rp2[w0 - 1] : 0.0f;
            xr[2][5] = (rv2 && rgt) ? rp2[w0 + 4] : 0.0f;
            xr[0][1] = m0.x; xr[0][2] = m0.y; xr[0][3] = m0.z; xr[0][4] = m0.w;
            xr[1][1] = m1.x; xr[1][2] = m1.y; xr[1][3] = m1.z; xr[1][4] = m1.w;
            xr[2][1] = m2.x; xr[2][2] = m2.y; xr[2][3] = m2.z; xr[2][4] = m2.w;
        }

        // neighbors[n, c, :]: block-uniform -> scalar loads
        float nb[9];
        #pragma unroll
        for (int k = 0; k < 9; ++k)
            nb[k] = neighbors[(n * CC + c) * 9 + k];

        // k=0 (rr=0,cc2=0) seeds: sample xr[2][j+2]
        float acc0 = fabsf(xr[2][2] - nb[0]);
        float acc1 = fabsf(xr[2][3] - nb[0]);
        float acc2 = fabsf(xr[2][4] - nb[0]);
        float acc3 = fabsf(xr[2][5] - nb[0]);
        #pragma unroll
        for (int kk = 1; kk < 9; ++kk) {
            const int rr  = kk / 3;       // row+1
            const int cc2 = kk - rr * 3;  // col+1
            const float nv = nb[kk];
            acc0 = fmaxf(acc0, fabsf(xr[2 - rr][0 + 2 - cc2] - nv));
            acc1 = fmaxf(acc1, fabsf(xr[2 - rr][1 + 2 - cc2] - nv));
            acc2 = fmaxf(acc2, fabsf(xr[2 - rr][2 + 2 - cc2] - nv));
            acc3 = fmaxf(acc3, fabsf(xr[2 - rr][3 + 2 - cc2] - nv));
        }
        f32x4 v = { acc0, acc1, acc2, acc3 };
        *reinterpret_cast<f32x4*>(obase + ci * (HH * WW)) = v;
    }
}

extern "C" void kernel_launch(void* const* d_in, const int* in_sizes, int n_in,
                              void* d_out, int out_size, void* d_ws, size_t ws_size,
                              hipStream_t stream) {
    const float* x         = (const float*)d_in[0];
    const float* neighbors = (const float*)d_in[1];
    float* out             = (float*)d_out;

    dim3 grid(BB * NUMN, CC / CPB);   // (512, 4) = 2048 blocks
    dim3 block(256);
    conv_nn_kernel<<<grid, block, 0, stream>>>(x, neighbors, out);
}

// Round 8
// 82.507 us; speedup vs baseline: 1.2049x; 1.2049x over previous
//
#include <hip/hip_runtime.h>

// ConvNearestNeighbor forward, MI355X (gfx950).
// x: (B=16, C=32, H=32, W=32) f32; neighbors: (NUM=32, C=32, 9) f32
// out[((b*NUM + n)*C + c)*H*W + h*W + w]
//   = max_k | x[b,c,h-row_k,w-col_k] (zero-pad) - neighbors[n,c,k] |,
//   k = 3*(row+1)+(col+1), row,col in {-1,0,1}
//
// Round 8: REVERT to round-6 zero-LDS kernel (best: 83.7 us).
// Round 7's contiguous-store remap regressed to 99.4 us: 4x read-instruction
// amplification (72 vs 9 VMEM reads/thread) — proving (a) kernel time is
// visible in dur_us, (b) the 4KB-chunk store pattern was already saturating.
// Model: dur_us ~= 45.5us poison fill + ~25us harness restores + ~13us kernel;
// pure store floor = 11.2us. This kernel is within ~2us of the write roofline.

#define BB 16
#define CC 32
#define HH 32
#define WW 32
#define NUMN 32
#define NPB 4    // codebook entries per block

typedef float f32x4 __attribute__((ext_vector_type(4)));

__global__ __launch_bounds__(256) void conv_nn_kernel(
    const float* __restrict__ x,
    const float* __restrict__ neighbors,
    float* __restrict__ out)
{
    const int bc = blockIdx.x;        // 0 .. B*C-1
    const int b  = bc >> 5;           // / C
    const int c  = bc & 31;           // % C
    const int n0 = blockIdx.y * NPB;  // first codebook entry for this block
    const int t  = threadIdx.x;       // 0..255

    // thread -> (h, w0..w0+3); plane-linear offset = h*W + w0 = 4*t
    const int h  = t >> 3;
    const int w0 = (t & 7) * 4;       // 16B-aligned column of the float4

    const float* __restrict__ xplane = x + (b * CC + c) * (HH * WW);

    // 3x6 zero-padded window: xr[r][j] = x[b,c, h-1+r, w0-1+j] (0 outside)
    float xr[3][6];
    #pragma unroll
    for (int r = 0; r < 3; ++r) {
        const int row = h - 1 + r;
        const bool rv = (unsigned)row < (unsigned)HH;
        const float* rp = xplane + row * WW;
        f32x4 mid = {0.0f, 0.0f, 0.0f, 0.0f};
        if (rv) mid = *reinterpret_cast<const f32x4*>(rp + w0);     // aligned
        const float left  = (rv && w0 > 0)      ? rp[w0 - 1] : 0.0f;
        const float right = (rv && w0 + 4 < WW) ? rp[w0 + 4] : 0.0f;
        xr[r][0] = left;  xr[r][1] = mid.x; xr[r][2] = mid.y;
        xr[r][3] = mid.z; xr[r][4] = mid.w; xr[r][5] = right;
    }

    // neighbors for this block: indices are wave-uniform -> s_load broadcasts
    float nb[NPB][9];
    #pragma unroll
    for (int ni = 0; ni < NPB; ++ni)
        #pragma unroll
        for (int k = 0; k < 9; ++k)
            nb[ni][k] = neighbors[((n0 + ni) * CC + c) * 9 + k];

    float* oplane = out + (size_t)((b * NUMN + n0) * CC + c) * (HH * WW) + t * 4;
    const int nstride = CC * HH * WW;   // plane stride between consecutive n

    #pragma unroll
    for (int ni = 0; ni < NPB; ++ni) {
        // k=0 (rr=0,cc2=0) seeds the max: sample xr[2][j+2]
        float acc0 = fabsf(xr[2][2] - nb[ni][0]);
        float acc1 = fabsf(xr[2][3] - nb[ni][0]);
        float acc2 = fabsf(xr[2][4] - nb[ni][0]);
        float acc3 = fabsf(xr[2][5] - nb[ni][0]);
        #pragma unroll
        for (int kk = 1; kk < 9; ++kk) {
            const int rr  = kk / 3;       // row+1
            const int cc2 = kk - rr * 3;  // col+1
            const float nv = nb[ni][kk];
            acc0 = fmaxf(acc0, fabsf(xr[2 - rr][0 + 2 - cc2] - nv));
            acc1 = fmaxf(acc1, fabsf(xr[2 - rr][1 + 2 - cc2] - nv));
            acc2 = fmaxf(acc2, fabsf(xr[2 - rr][2 + 2 - cc2] - nv));
            acc3 = fmaxf(acc3, fabsf(xr[2 - rr][3 + 2 - cc2] - nv));
        }
        f32x4 v = { acc0, acc1, acc2, acc3 };
        *reinterpret_cast<f32x4*>(oplane + (size_t)ni * nstride) = v;
    }
}

extern "C" void kernel_launch(void* const* d_in, const int* in_sizes, int n_in,
                              void* d_out, int out_size, void* d_ws, size_t ws_size,
                              hipStream_t stream) {
    const float* x         = (const float*)d_in[0];
    const float* neighbors = (const float*)d_in[1];
    float* out             = (float*)d_out;

    dim3 grid(BB * CC, NUMN / NPB);   // (512, 8) = 4096 blocks
    dim3 block(256);
    conv_nn_kernel<<<grid, block, 0, stream>>>(x, neighbors, out);
}